// Round 1
// baseline (1625.067 us; speedup 1.0000x reference)
//
#include <hip/hip_runtime.h>
#include <stdint.h>

typedef __attribute__((ext_vector_type(8))) short short8;
typedef __attribute__((ext_vector_type(4))) float f32x4;

#define T_STEPS 200
#define BATCH   128
#define UNITS   256
#define N3      768
#define EMB_D   100

// cluster config: 16 row-groups x 8 col-chunk blocks = 128 blocks
#define NG 16
#define NC 8
#define RR 8        // batch rows per group
#define NBCOL 96    // output cols per block
#define NTILE 6     // 16-wide col tiles per block

#define WFR_ELEMS (NC * NTILE * 8 * 64 * 8)  // 196608 == 256*768
#define WFX_ELEMS (48 * 4 * 64 * 8)          // 98304  == 128*768 (K padded 100->128)

__device__ __forceinline__ unsigned short f2bf(float f) {
  unsigned int u = __float_as_uint(f);
  u = (u + 0x7fffu + ((u >> 16) & 1u)) >> 16;   // RNE
  return (unsigned short)u;
}
__device__ __forceinline__ float bf2f(unsigned short s) {
  return __uint_as_float(((unsigned int)s) << 16);
}
__device__ __forceinline__ float sigmoidf_(float x) { return 1.0f / (1.0f + __expf(-x)); }
__device__ __forceinline__ float tanhf_(float x)    { return 1.0f - 2.0f / (1.0f + __expf(2.0f * x)); }

// ---------------- kernel 0: weight prep (frag-order bf16) + bias fold + flag reset ----
__global__ void prep_kernel(const float* __restrict__ kern,
                            const float* __restrict__ rkern,
                            const float* __restrict__ bias_i,
                            const float* __restrict__ bias_r,
                            unsigned short* __restrict__ wfr,
                            unsigned short* __restrict__ wfx,
                            float* __restrict__ bsum,
                            int* __restrict__ flags) {
  int i = blockIdx.x * 256 + threadIdx.x;
  if (i < WFR_ELEMS) {
    // [cb][nt][ks][lane][e] -> rkernel[k][n]
    int e = i & 7, l = (i >> 3) & 63, ks = (i >> 9) & 7;
    int rem = i >> 12; int nt = rem % 6; int cb = rem / 6;
    int k = ks * 32 + (e >> 2) * 16 + ((l >> 4) & 3) * 4 + (e & 3);
    int n = cb * NBCOL + nt * 16 + (l & 15);
    wfr[i] = f2bf(rkern[k * N3 + n]);
  } else if (i < WFR_ELEMS + WFX_ELEMS) {
    int j = i - WFR_ELEMS;
    int e = j & 7, l = (j >> 3) & 63, ks = (j >> 9) & 3, nt = j >> 11;
    int k = ks * 32 + (e >> 2) * 16 + ((l >> 4) & 3) * 4 + (e & 3);
    int n = nt * 16 + (l & 15);
    wfx[j] = (k < EMB_D) ? f2bf(kern[k * N3 + n]) : (unsigned short)0;
  } else if (i < WFR_ELEMS + WFX_ELEMS + N3) {
    // bias_i for all cols; bias_r folded for z,r parts (c part applied inside r*(...))
    int c = i - (WFR_ELEMS + WFX_ELEMS);
    bsum[c] = bias_i[c] + ((c < 2 * UNITS) ? bias_r[c] : 0.0f);
  } else if (i < WFR_ELEMS + WFX_ELEMS + N3 + NG * NC) {
    flags[i - (WFR_ELEMS + WFX_ELEMS + N3)] = 0;
  }
}

// ---------------- kernel 1: MX[t][b][768] = emb[inputs] @ kernel + bsum (bf16 out) ----
__global__ __launch_bounds__(256, 1) void mx_kernel(
    const int* __restrict__ inputs, const float* __restrict__ emb,
    const unsigned short* __restrict__ wfx, const float* __restrict__ bsum,
    unsigned short* __restrict__ MX) {
  __shared__ unsigned short Af[4 * 64 * 8];  // A fragments, 16 rows x K128, 4KB
  int tile = blockIdx.x;                      // 1600 tiles of 16 (t,b) rows
  int tid = threadIdx.x;
  int lane = tid & 63;
  int wv = tid >> 6;
  {
    short8 z = {0, 0, 0, 0, 0, 0, 0, 0};
    ((short8*)Af)[tid] = z;                   // 256*8 = 2048 entries
  }
  __syncthreads();
  for (int e = tid; e < 16 * EMB_D; e += 256) {
    int r = e / EMB_D;
    int c = e - r * EMB_D;
    int m = tile * 16 + r;                    // m = t*128 + b (time-major rows)
    int ti = m >> 7, b = m & 127;
    int word = inputs[b * T_STEPS + ti];
    float v = emb[word * EMB_D + c];
    int idx = ((c >> 5) * 64 + (r + 16 * ((c >> 2) & 3))) * 8 + ((c >> 4) & 1) * 4 + (c & 3);
    Af[idx] = f2bf(v);
  }
  __syncthreads();
  short8 a0 = ((short8*)Af)[0 * 64 + lane];
  short8 a1 = ((short8*)Af)[1 * 64 + lane];
  short8 a2 = ((short8*)Af)[2 * 64 + lane];
  short8 a3 = ((short8*)Af)[3 * 64 + lane];
  int r0 = (lane >> 4) * 4;
  for (int q = 0; q < 12; ++q) {
    int nt = wv * 12 + q;
    f32x4 acc = {0.f, 0.f, 0.f, 0.f};
    const short8* bp = (const short8*)(wfx) + (nt * 4) * 64 + lane;
    acc = __builtin_amdgcn_mfma_f32_16x16x32_bf16(a0, bp[0],   acc, 0, 0, 0);
    acc = __builtin_amdgcn_mfma_f32_16x16x32_bf16(a1, bp[64],  acc, 0, 0, 0);
    acc = __builtin_amdgcn_mfma_f32_16x16x32_bf16(a2, bp[128], acc, 0, 0, 0);
    acc = __builtin_amdgcn_mfma_f32_16x16x32_bf16(a3, bp[192], acc, 0, 0, 0);
    int col = nt * 16 + (lane & 15);
    float bs = bsum[col];
#pragma unroll
    for (int j = 0; j < 4; ++j) {
      int m = tile * 16 + r0 + j;
      MX[(size_t)m * N3 + col] = f2bf(acc[j] + bs);
    }
  }
}

// ---------------- kernel 2: persistent clustered GRU recurrence ----------------------
__global__ __launch_bounds__(256, 1) void gru_kernel(
    const unsigned short* __restrict__ MX, const unsigned short* __restrict__ wfr,
    float* __restrict__ mh, int* __restrict__ flags,
    const float* __restrict__ bias_r, const float* __restrict__ w_out,
    const float* __restrict__ b_out, float* __restrict__ out) {
  __shared__ unsigned short Wlds[NTILE * 8 * 64 * 8];  // 49152 B weight slice
  __shared__ unsigned short hA[8 * 64 * 8];            // 8192 B  h A-fragments (M=16, rows 8..15 stay 0)
  int bx = blockIdx.x;
  int g  = (bx & 7) * 2 + (bx >> 6);   // cluster peers share XCD (heuristic only)
  int cb = (bx >> 3) & 7;
  int tid = threadIdx.x;
  int lane = tid & 63;
  int wv = tid >> 6;

  {
    const short8* src = (const short8*)(wfr) + cb * (NTILE * 8 * 64);
    short8* dst = (short8*)Wlds;
    for (int i = tid; i < NTILE * 8 * 64; i += 256) dst[i] = src[i];
  }
  {
    short8 z = {0, 0, 0, 0, 0, 0, 0, 0};
    short8* dst = (short8*)hA;
    for (int i = tid; i < 8 * 64; i += 256) dst[i] = z;
  }

  int row = tid >> 5;              // 0..7 local batch row
  int u0 = (tid & 31) * 8;         // unit range [u0, u0+8)
  int grow = g * RR + row;         // global batch row

  float hreg[8];
#pragma unroll
  for (int j = 0; j < 8; ++j) hreg[j] = 0.0f;
  float brc[8];
#pragma unroll
  for (int j = 0; j < 8; ++j) brc[j] = bias_r[2 * UNITS + u0 + j];

  int hidx[8];
#pragma unroll
  for (int j = 0; j < 8; ++j) {
    int u = u0 + j;
    hidx[j] = ((u >> 5) * 64 + (row + 16 * ((u >> 2) & 3))) * 8 + ((u >> 4) & 1) * 4 + (u & 3);
  }

  int nt_cnt  = (wv < 2) ? 2 : 1;
  int nt_base = (wv < 2) ? wv * 2 : 2 + wv;   // waves: [0,1],[2,3],[4],[5]
  int r0 = (lane >> 4) * 4;
  int colbase = cb * NBCOL + (lane & 15);

  __syncthreads();

  for (int t = 0; t < T_STEPS; ++t) {
    // prefetch mx for this step (consumed after the sync point -> latency hidden)
    const unsigned short* mxp = MX + ((size_t)t * BATCH + grow) * N3 + u0;
    short8 vz = *(const short8*)(mxp);
    short8 vr = *(const short8*)(mxp + UNITS);
    short8 vc = *(const short8*)(mxp + 2 * UNITS);

    // GEMV: mh chunk [RR x NBCOL] = h @ W_slice (bf16 MFMA, fp32 acc)
    short8 a[8];
#pragma unroll
    for (int ks = 0; ks < 8; ++ks) a[ks] = ((short8*)hA)[ks * 64 + lane];

    float* mhb = mh + ((size_t)(t & 1) * NG + g) * (RR * N3);
    for (int q = 0; q < nt_cnt; ++q) {
      int nt = nt_base + q;
      f32x4 acc = {0.f, 0.f, 0.f, 0.f};
#pragma unroll
      for (int ks = 0; ks < 8; ++ks) {
        short8 bfrag = ((short8*)Wlds)[(nt * 8 + ks) * 64 + lane];
        acc = __builtin_amdgcn_mfma_f32_16x16x32_bf16(a[ks], bfrag, acc, 0, 0, 0);
      }
      if (r0 < RR) {                       // D rows 0..7 valid (lanes 0..31)
        int col = colbase + nt * 16;
#pragma unroll
        for (int j = 0; j < 4; ++j) mhb[(r0 + j) * N3 + col] = acc[j];
      }
    }

    __syncthreads();   // all waves' chunk stores drained (vmcnt0 before barrier)

    if (tid == 0)
      __hip_atomic_store(&flags[g * NC + cb], t + 1, __ATOMIC_RELEASE, __HIP_MEMORY_SCOPE_AGENT);
    if (tid < NC && tid != cb) {
      int it = 0;
      while (__hip_atomic_load(&flags[g * NC + tid], __ATOMIC_RELAXED, __HIP_MEMORY_SCOPE_AGENT) < t + 1) {
        __builtin_amdgcn_s_sleep(1);
        if (++it > (1 << 18)) break;       // safety: fail visibly, never hang
      }
    }
    __atomic_thread_fence(__ATOMIC_ACQUIRE);  // invalidate L1/L2 so peer chunks are fresh
    __syncthreads();

    // gate phase: full h update (redundant across the 8 cluster blocks)
    const float* mhr = mhb + row * N3 + u0;
    f32x4 hz0 = *(const f32x4*)(mhr);
    f32x4 hz1 = *(const f32x4*)(mhr + 4);
    f32x4 hr0 = *(const f32x4*)(mhr + UNITS);
    f32x4 hr1 = *(const f32x4*)(mhr + UNITS + 4);
    f32x4 hc0 = *(const f32x4*)(mhr + 2 * UNITS);
    f32x4 hc1 = *(const f32x4*)(mhr + 2 * UNITS + 4);
#pragma unroll
    for (int j = 0; j < 8; ++j) {
      float xz = bf2f((unsigned short)vz[j]);
      float xr = bf2f((unsigned short)vr[j]);
      float xc = bf2f((unsigned short)vc[j]);
      float hzv = (j < 4) ? hz0[j] : hz1[j - 4];
      float hrv = (j < 4) ? hr0[j] : hr1[j - 4];
      float hcv = (j < 4) ? hc0[j] : hc1[j - 4];
      float z = sigmoidf_(xz + hzv);          // bias_i + bias_r(z) folded into MX
      float r = sigmoidf_(xr + hrv);          // bias_i + bias_r(r) folded into MX
      float cand = tanhf_(xc + r * (hcv + brc[j]));  // bias_r(c) inside r*(...)
      hreg[j] = z * hreg[j] + (1.0f - z) * cand;
      hA[hidx[j]] = f2bf(hreg[j]);
    }
    __syncthreads();
  }

  if (cb == 0) {
    float p = 0.0f;
#pragma unroll
    for (int j = 0; j < 8; ++j) p += hreg[j] * w_out[u0 + j];
    p += __shfl_down(p, 16, 32);
    p += __shfl_down(p, 8, 32);
    p += __shfl_down(p, 4, 32);
    p += __shfl_down(p, 2, 32);
    p += __shfl_down(p, 1, 32);
    if ((tid & 31) == 0) out[grow] = sigmoidf_(p + b_out[0]);
  }
}

extern "C" void kernel_launch(void* const* d_in, const int* in_sizes, int n_in,
                              void* d_out, int out_size, void* d_ws, size_t ws_size,
                              hipStream_t stream) {
  const int*   inputs = (const int*)d_in[0];
  const float* emb    = (const float*)d_in[1];
  const float* kern   = (const float*)d_in[2];
  const float* rkern  = (const float*)d_in[3];
  const float* bias_i = (const float*)d_in[4];
  const float* bias_r = (const float*)d_in[5];
  const float* w_out  = (const float*)d_in[6];
  const float* b_out  = (const float*)d_in[7];
  float* out = (float*)d_out;

  char* ws = (char*)d_ws;
  size_t off = 0;
  unsigned short* MX  = (unsigned short*)(ws + off); off += (size_t)T_STEPS * BATCH * N3 * 2; // 39.3 MB
  unsigned short* wfr = (unsigned short*)(ws + off); off += (size_t)WFR_ELEMS * 2;            // 384 KB
  unsigned short* wfx = (unsigned short*)(ws + off); off += (size_t)WFX_ELEMS * 2;            // 192 KB
  float* bsum = (float*)(ws + off); off += (size_t)N3 * 4;
  float* mh   = (float*)(ws + off); off += (size_t)2 * NG * RR * N3 * 4;                       // 768 KB
  int* flags  = (int*)(ws + off);   off += 1024;
  if (off > ws_size) return;  // insufficient scratch -> visible failure, no corruption

  int prep_total = WFR_ELEMS + WFX_ELEMS + N3 + NG * NC;
  prep_kernel<<<dim3((prep_total + 255) / 256), dim3(256), 0, stream>>>(
      kern, rkern, bias_i, bias_r, wfr, wfx, bsum, flags);
  mx_kernel<<<dim3(1600), dim3(256), 0, stream>>>(inputs, emb, wfx, bsum, MX);
  gru_kernel<<<dim3(128), dim3(256), 0, stream>>>(MX, wfr, mh, flags, bias_r, w_out, b_out, out);
}

// Round 2
// 547.404 us; speedup vs baseline: 2.9687x; 2.9687x over previous
//
#include <hip/hip_runtime.h>
#include <stdint.h>

typedef __attribute__((ext_vector_type(8))) short short8;
typedef __attribute__((ext_vector_type(4))) short short4v;
typedef __attribute__((ext_vector_type(4))) float f32x4;

#define T_STEPS 200
#define BATCH   128
#define UNITS   256
#define N3      768
#define EMB_D   100

#define NG 16       // row groups (blocks in gru kernel)
#define RR 8        // batch rows per group
#define QT 12       // 16-col ntiles per wave (4 waves x 12 x 16 = 768)

#define WFR_ELEMS (48 * 8 * 64 * 8)          // 196608 == 256*768  (48 global ntiles)
#define WFX_ELEMS (48 * 4 * 64 * 8)          // 98304  == 128*768 (K padded 100->128)

__device__ __forceinline__ unsigned short f2bf(float f) {
  unsigned int u = __float_as_uint(f);
  u = (u + 0x7fffu + ((u >> 16) & 1u)) >> 16;   // RNE
  return (unsigned short)u;
}
__device__ __forceinline__ float bf2f(unsigned short s) {
  return __uint_as_float(((unsigned int)s) << 16);
}
__device__ __forceinline__ float sigmoidf_(float x) { return 1.0f / (1.0f + __expf(-x)); }
__device__ __forceinline__ float tanhf_(float x)    { return 1.0f - 2.0f / (1.0f + __expf(2.0f * x)); }

// ---------------- kernel 0: weight prep (frag-order bf16) + bias fold ----------------
__global__ void prep_kernel(const float* __restrict__ kern,
                            const float* __restrict__ rkern,
                            const float* __restrict__ bias_i,
                            const float* __restrict__ bias_r,
                            unsigned short* __restrict__ wfr,
                            unsigned short* __restrict__ wfx,
                            float* __restrict__ bsum) {
  int i = blockIdx.x * 256 + threadIdx.x;
  if (i < WFR_ELEMS) {
    // [ntg][ks][lane][e] -> rkernel[k][n], ntg = global 16-col tile 0..47
    int e = i & 7, l = (i >> 3) & 63, ks = (i >> 9) & 7, ntg = i >> 12;
    int k = ks * 32 + (e >> 2) * 16 + ((l >> 4) & 3) * 4 + (e & 3);
    int n = ntg * 16 + (l & 15);
    wfr[i] = f2bf(rkern[k * N3 + n]);
  } else if (i < WFR_ELEMS + WFX_ELEMS) {
    int j = i - WFR_ELEMS;
    int e = j & 7, l = (j >> 3) & 63, ks = (j >> 9) & 3, nt = j >> 11;
    int k = ks * 32 + (e >> 2) * 16 + ((l >> 4) & 3) * 4 + (e & 3);
    int n = nt * 16 + (l & 15);
    wfx[j] = (k < EMB_D) ? f2bf(kern[k * N3 + n]) : (unsigned short)0;
  } else if (i < WFR_ELEMS + WFX_ELEMS + N3) {
    // bias_i for all cols; bias_r folded for z,r parts (c part applied inside r*(...))
    int c = i - (WFR_ELEMS + WFX_ELEMS);
    bsum[c] = bias_i[c] + ((c < 2 * UNITS) ? bias_r[c] : 0.0f);
  }
}

// ---------------- kernel 1: MX[t][b][768] = emb[inputs] @ kernel + bsum (bf16 out) ----
__global__ __launch_bounds__(256, 1) void mx_kernel(
    const int* __restrict__ inputs, const float* __restrict__ emb,
    const unsigned short* __restrict__ wfx, const float* __restrict__ bsum,
    unsigned short* __restrict__ MX) {
  __shared__ unsigned short Af[4 * 64 * 8];  // A fragments, 16 rows x K128, 4KB
  int tile = blockIdx.x;                      // 1600 tiles of 16 (t,b) rows
  int tid = threadIdx.x;
  int lane = tid & 63;
  int wv = tid >> 6;
  {
    short8 z = {0, 0, 0, 0, 0, 0, 0, 0};
    ((short8*)Af)[tid] = z;                   // 256*8 = 2048 entries
  }
  __syncthreads();
  for (int e = tid; e < 16 * EMB_D; e += 256) {
    int r = e / EMB_D;
    int c = e - r * EMB_D;
    int m = tile * 16 + r;                    // m = t*128 + b (time-major rows)
    int ti = m >> 7, b = m & 127;
    int word = inputs[b * T_STEPS + ti];
    float v = emb[word * EMB_D + c];
    int idx = ((c >> 5) * 64 + (r + 16 * ((c >> 2) & 3))) * 8 + ((c >> 4) & 1) * 4 + (c & 3);
    Af[idx] = f2bf(v);
  }
  __syncthreads();
  short8 a0 = ((short8*)Af)[0 * 64 + lane];
  short8 a1 = ((short8*)Af)[1 * 64 + lane];
  short8 a2 = ((short8*)Af)[2 * 64 + lane];
  short8 a3 = ((short8*)Af)[3 * 64 + lane];
  int r0 = (lane >> 4) * 4;
  for (int q = 0; q < 12; ++q) {
    int nt = wv * 12 + q;
    f32x4 acc = {0.f, 0.f, 0.f, 0.f};
    const short8* bp = (const short8*)(wfx) + (nt * 4) * 64 + lane;
    acc = __builtin_amdgcn_mfma_f32_16x16x32_bf16(a0, bp[0],   acc, 0, 0, 0);
    acc = __builtin_amdgcn_mfma_f32_16x16x32_bf16(a1, bp[64],  acc, 0, 0, 0);
    acc = __builtin_amdgcn_mfma_f32_16x16x32_bf16(a2, bp[128], acc, 0, 0, 0);
    acc = __builtin_amdgcn_mfma_f32_16x16x32_bf16(a3, bp[192], acc, 0, 0, 0);
    int col = nt * 16 + (lane & 15);
    float bs = bsum[col];
#pragma unroll
    for (int j = 0; j < 4; ++j) {
      int m = tile * 16 + r0 + j;
      MX[(size_t)m * N3 + col] = f2bf(acc[j] + bs);
    }
  }
}

// ---------------- kernel 2: block-local GRU recurrence, weights in registers ---------
__global__ __launch_bounds__(256, 1) void gru_kernel(
    const unsigned short* __restrict__ MX, const unsigned short* __restrict__ wfr,
    const float* __restrict__ bias_r, const float* __restrict__ w_out,
    const float* __restrict__ b_out, float* __restrict__ out) {
  __shared__ unsigned short hA[8 * 64 * 8];   // 8 KB: h as A-frags, M=16 (rows 8..15 zero)
  __shared__ float mhs[RR * N3];              // 24 KB: mh exchange buffer

  int g = blockIdx.x;                          // row group 0..15
  int tid = threadIdx.x;
  int lane = tid & 63;
  int wv = tid >> 6;

  // persistent weight fragments: wave wv owns cols [wv*192, wv*192+192)
  short8 wb[QT][8];
  {
    const short8* wsrc = (const short8*)wfr + (size_t)(wv * QT) * 8 * 64 + lane;
#pragma unroll
    for (int q = 0; q < QT; ++q)
#pragma unroll
      for (int ks = 0; ks < 8; ++ks)
        wb[q][ks] = wsrc[(q * 8 + ks) * 64];
  }

  {
    short8 z = {0, 0, 0, 0, 0, 0, 0, 0};
    for (int i = tid; i < 8 * 64; i += 256) ((short8*)hA)[i] = z;
  }

  int row = tid >> 5;              // 0..7 local batch row
  int u0 = (tid & 31) * 8;         // unit range [u0, u0+8)
  int grow = g * RR + row;         // global batch row

  float hreg[8];
#pragma unroll
  for (int j = 0; j < 8; ++j) hreg[j] = 0.0f;
  float brc[8];
#pragma unroll
  for (int j = 0; j < 8; ++j) brc[j] = bias_r[2 * UNITS + u0 + j];

  // hA write bases for this thread's (row, u0..u0+7): two runs of 4 consecutive shorts
  int hbase0, hbase4;
  {
    int u = u0;
    hbase0 = ((u >> 5) * 64 + (row + 16 * ((u >> 2) & 3))) * 8 + ((u >> 4) & 1) * 4;
    u = u0 + 4;
    hbase4 = ((u >> 5) * 64 + (row + 16 * ((u >> 2) & 3))) * 8 + ((u >> 4) & 1) * 4;
  }

  int r0 = (lane >> 4) * 4;                 // D-fragment row base
  int colbase = wv * (QT * 16) + (lane & 15);
  const unsigned short* mxp = MX + (size_t)grow * N3 + u0;

  __syncthreads();

  for (int t = 0; t < T_STEPS; ++t) {
    // prefetch mx for this step (consumed after barrier -> latency hidden)
    short8 vz = *(const short8*)(mxp);
    short8 vr = *(const short8*)(mxp + UNITS);
    short8 vc = *(const short8*)(mxp + 2 * UNITS);
    mxp += (size_t)BATCH * N3;

    // A-fragments of h (M=16, rows 8..15 zero)
    short8 a[8];
#pragma unroll
    for (int ks = 0; ks < 8; ++ks) a[ks] = ((short8*)hA)[ks * 64 + lane];

    // GEMV: mh[row][col] = h @ rkernel, 12 ntiles in 3 groups of 4 interleaved chains
#pragma unroll
    for (int gq = 0; gq < 3; ++gq) {
      f32x4 acc0 = {0.f, 0.f, 0.f, 0.f};
      f32x4 acc1 = {0.f, 0.f, 0.f, 0.f};
      f32x4 acc2 = {0.f, 0.f, 0.f, 0.f};
      f32x4 acc3 = {0.f, 0.f, 0.f, 0.f};
#pragma unroll
      for (int ks = 0; ks < 8; ++ks) {
        acc0 = __builtin_amdgcn_mfma_f32_16x16x32_bf16(a[ks], wb[gq * 4 + 0][ks], acc0, 0, 0, 0);
        acc1 = __builtin_amdgcn_mfma_f32_16x16x32_bf16(a[ks], wb[gq * 4 + 1][ks], acc1, 0, 0, 0);
        acc2 = __builtin_amdgcn_mfma_f32_16x16x32_bf16(a[ks], wb[gq * 4 + 2][ks], acc2, 0, 0, 0);
        acc3 = __builtin_amdgcn_mfma_f32_16x16x32_bf16(a[ks], wb[gq * 4 + 3][ks], acc3, 0, 0, 0);
      }
      if (r0 < RR) {                       // D rows 0..7 valid (lanes 0..31)
#pragma unroll
        for (int j = 0; j < 4; ++j) {
          int rbase = (r0 + j) * N3 + colbase + gq * 64;
          mhs[rbase]      = acc0[j];
          mhs[rbase + 16] = acc1[j];
          mhs[rbase + 32] = acc2[j];
          mhs[rbase + 48] = acc3[j];
        }
      }
    }

    __syncthreads();   // mh visible; all a-frag reads done

    // gate phase: h update (each thread: its row, 8 units)
    const float* mhr = mhs + row * N3 + u0;
    f32x4 hz0 = *(const f32x4*)(mhr);
    f32x4 hz1 = *(const f32x4*)(mhr + 4);
    f32x4 hr0 = *(const f32x4*)(mhr + UNITS);
    f32x4 hr1 = *(const f32x4*)(mhr + UNITS + 4);
    f32x4 hc0 = *(const f32x4*)(mhr + 2 * UNITS);
    f32x4 hc1 = *(const f32x4*)(mhr + 2 * UNITS + 4);
    unsigned short hb[8];
#pragma unroll
    for (int j = 0; j < 8; ++j) {
      float xz = bf2f((unsigned short)vz[j]);
      float xr = bf2f((unsigned short)vr[j]);
      float xc = bf2f((unsigned short)vc[j]);
      float hzv = (j < 4) ? hz0[j] : hz1[j - 4];
      float hrv = (j < 4) ? hr0[j] : hr1[j - 4];
      float hcv = (j < 4) ? hc0[j] : hc1[j - 4];
      float z = sigmoidf_(xz + hzv);          // bias_i + bias_r(z) folded into MX
      float r = sigmoidf_(xr + hrv);          // bias_i + bias_r(r) folded into MX
      float cand = tanhf_(xc + r * (hcv + brc[j]));  // bias_r(c) inside r*(...)
      hreg[j] = z * hreg[j] + (1.0f - z) * cand;
      hb[j] = f2bf(hreg[j]);
    }
    {
      short4v p0 = { (short)hb[0], (short)hb[1], (short)hb[2], (short)hb[3] };
      short4v p1 = { (short)hb[4], (short)hb[5], (short)hb[6], (short)hb[7] };
      *(short4v*)&hA[hbase0] = p0;
      *(short4v*)&hA[hbase4] = p1;
    }
    __syncthreads();
  }

  // output: logits = h1 @ w_out + b_out -> sigmoid
  {
    float p = 0.0f;
#pragma unroll
    for (int j = 0; j < 8; ++j) p += hreg[j] * w_out[u0 + j];
    p += __shfl_down(p, 16, 32);
    p += __shfl_down(p, 8, 32);
    p += __shfl_down(p, 4, 32);
    p += __shfl_down(p, 2, 32);
    p += __shfl_down(p, 1, 32);
    if ((tid & 31) == 0) out[grow] = sigmoidf_(p + b_out[0]);
  }
}

extern "C" void kernel_launch(void* const* d_in, const int* in_sizes, int n_in,
                              void* d_out, int out_size, void* d_ws, size_t ws_size,
                              hipStream_t stream) {
  const int*   inputs = (const int*)d_in[0];
  const float* emb    = (const float*)d_in[1];
  const float* kern   = (const float*)d_in[2];
  const float* rkern  = (const float*)d_in[3];
  const float* bias_i = (const float*)d_in[4];
  const float* bias_r = (const float*)d_in[5];
  const float* w_out  = (const float*)d_in[6];
  const float* b_out  = (const float*)d_in[7];
  float* out = (float*)d_out;

  char* ws = (char*)d_ws;
  size_t off = 0;
  unsigned short* MX  = (unsigned short*)(ws + off); off += (size_t)T_STEPS * BATCH * N3 * 2; // 39.3 MB
  unsigned short* wfr = (unsigned short*)(ws + off); off += (size_t)WFR_ELEMS * 2;            // 384 KB
  unsigned short* wfx = (unsigned short*)(ws + off); off += (size_t)WFX_ELEMS * 2;            // 192 KB
  float* bsum = (float*)(ws + off); off += (size_t)N3 * 4;
  if (off > ws_size) return;  // insufficient scratch -> visible failure, no corruption

  int prep_total = WFR_ELEMS + WFX_ELEMS + N3;
  prep_kernel<<<dim3((prep_total + 255) / 256), dim3(256), 0, stream>>>(
      kern, rkern, bias_i, bias_r, wfr, wfx, bsum);
  mx_kernel<<<dim3(1600), dim3(256), 0, stream>>>(inputs, emb, wfx, bsum, MX);
  gru_kernel<<<dim3(NG), dim3(256), 0, stream>>>(MX, wfr, bias_r, w_out, b_out, out);
}

// Round 3
// 403.335 us; speedup vs baseline: 4.0291x; 1.3572x over previous
//
#include <hip/hip_runtime.h>
#include <stdint.h>

typedef __attribute__((ext_vector_type(8))) short short8;
typedef __attribute__((ext_vector_type(4))) float f32x4;
typedef __attribute__((ext_vector_type(4))) int   i32x4;

#define T_STEPS 200
#define BATCH   128
#define UNITS   256
#define N3      768
#define EMB_D   100

#define NG 16       // row groups (blocks in gru kernel)
#define RR 8        // batch rows per group
#define GW 8        // waves per gru block
#define QW 6        // 16-col ntiles per wave (8 waves x 6 x 16 = 768)

#define W8_BYTES  (48 * 4 * 64 * 16)         // 196608 == 256*768 i8 frags
#define WFX_ELEMS (48 * 4 * 64 * 8)          // 98304  == 128*768 bf16 (K padded 100->128)

__device__ __forceinline__ unsigned short f2bf(float f) {
  unsigned int u = __float_as_uint(f);
  u = (u + 0x7fffu + ((u >> 16) & 1u)) >> 16;   // RNE
  return (unsigned short)u;
}
__device__ __forceinline__ float bf2f(unsigned short s) {
  return __uint_as_float(((unsigned int)s) << 16);
}
__device__ __forceinline__ float sigmoidf_(float x) { return 1.0f / (1.0f + __expf(-x)); }
__device__ __forceinline__ float tanhf_(float x)    { return 1.0f - 2.0f / (1.0f + __expf(2.0f * x)); }

// ---------------- kernel 0a: per-column absmax of rkernel -> cm[768] ----------------
__global__ void scale_kernel(const float* __restrict__ rkern, float* __restrict__ cm) {
  int n = blockIdx.x * 256 + threadIdx.x;   // 3 blocks x 256 = 768 cols
  if (n >= N3) return;
  float m = 0.0f;
  for (int k = 0; k < UNITS; ++k) m = fmaxf(m, fabsf(rkern[k * N3 + n]));
  cm[n] = (m > 0.0f) ? m : 1.0f;
}

// ---------------- kernel 0b: quantize rkernel->i8 frags, kernel->bf16 frags, bsum ---
__global__ void prep_kernel(const float* __restrict__ kern,
                            const float* __restrict__ rkern,
                            const float* __restrict__ bias_i,
                            const float* __restrict__ bias_r,
                            const float* __restrict__ cm,
                            signed char* __restrict__ w8,
                            unsigned short* __restrict__ wfx,
                            float* __restrict__ bsum) {
  int i = blockIdx.x * 256 + threadIdx.x;
  if (i < W8_BYTES) {
    // byte i = ((ntg*4 + kc)*64 + l)*16 + e  ->  rkernel[k][n] / cm[n] * 127
    int e = i & 15, l = (i >> 4) & 63, kc = (i >> 10) & 3, ntg = i >> 12;
    int r = (e & 3) + ((l >> 4) & 3) * 4 + ((e >> 2) & 3) * 16;  // k within 64-chunk
    int k = kc * 64 + r;
    int n = ntg * 16 + (l & 15);
    float v = rintf(rkern[k * N3 + n] * 127.0f / cm[n]);
    v = fminf(127.0f, fmaxf(-127.0f, v));
    w8[i] = (signed char)(int)v;
  } else if (i < W8_BYTES + WFX_ELEMS) {
    int j = i - W8_BYTES;
    int e = j & 7, l = (j >> 3) & 63, ks = (j >> 9) & 3, nt = j >> 11;
    int k = ks * 32 + (e >> 2) * 16 + ((l >> 4) & 3) * 4 + (e & 3);
    int n = nt * 16 + (l & 15);
    wfx[j] = (k < EMB_D) ? f2bf(kern[k * N3 + n]) : (unsigned short)0;
  } else if (i < W8_BYTES + WFX_ELEMS + N3) {
    int c = i - (W8_BYTES + WFX_ELEMS);
    bsum[c] = bias_i[c] + ((c < 2 * UNITS) ? bias_r[c] : 0.0f);
  }
}

// ---------------- kernel 1: MX[t][b][768] = emb[inputs] @ kernel + bsum (bf16 out) ----
__global__ __launch_bounds__(256, 1) void mx_kernel(
    const int* __restrict__ inputs, const float* __restrict__ emb,
    const unsigned short* __restrict__ wfx, const float* __restrict__ bsum,
    unsigned short* __restrict__ MX) {
  __shared__ unsigned short Af[4 * 64 * 8];  // A fragments, 16 rows x K128, 4KB
  int tile = blockIdx.x;                      // 1600 tiles of 16 (t,b) rows
  int tid = threadIdx.x;
  int lane = tid & 63;
  int wv = tid >> 6;
  {
    short8 z = {0, 0, 0, 0, 0, 0, 0, 0};
    ((short8*)Af)[tid] = z;
  }
  __syncthreads();
  for (int e = tid; e < 16 * EMB_D; e += 256) {
    int r = e / EMB_D;
    int c = e - r * EMB_D;
    int m = tile * 16 + r;                    // m = t*128 + b (time-major rows)
    int ti = m >> 7, b = m & 127;
    int word = inputs[b * T_STEPS + ti];
    float v = emb[word * EMB_D + c];
    int idx = ((c >> 5) * 64 + (r + 16 * ((c >> 2) & 3))) * 8 + ((c >> 4) & 1) * 4 + (c & 3);
    Af[idx] = f2bf(v);
  }
  __syncthreads();
  short8 a0 = ((short8*)Af)[0 * 64 + lane];
  short8 a1 = ((short8*)Af)[1 * 64 + lane];
  short8 a2 = ((short8*)Af)[2 * 64 + lane];
  short8 a3 = ((short8*)Af)[3 * 64 + lane];
  int r0 = (lane >> 4) * 4;
  for (int q = 0; q < 12; ++q) {
    int nt = wv * 12 + q;
    f32x4 acc = {0.f, 0.f, 0.f, 0.f};
    const short8* bp = (const short8*)(wfx) + (nt * 4) * 64 + lane;
    acc = __builtin_amdgcn_mfma_f32_16x16x32_bf16(a0, bp[0],   acc, 0, 0, 0);
    acc = __builtin_amdgcn_mfma_f32_16x16x32_bf16(a1, bp[64],  acc, 0, 0, 0);
    acc = __builtin_amdgcn_mfma_f32_16x16x32_bf16(a2, bp[128], acc, 0, 0, 0);
    acc = __builtin_amdgcn_mfma_f32_16x16x32_bf16(a3, bp[192], acc, 0, 0, 0);
    int col = nt * 16 + (lane & 15);
    float bs = bsum[col];
#pragma unroll
    for (int j = 0; j < 4; ++j) {
      int m = tile * 16 + r0 + j;
      MX[(size_t)m * N3 + col] = f2bf(acc[j] + bs);
    }
  }
}

// ---------------- kernel 2: block-local GRU recurrence, i8 MFMA, 8 waves -------------
__global__ __launch_bounds__(512, 2) void gru_kernel(
    const unsigned short* __restrict__ MX, const signed char* __restrict__ w8,
    const float* __restrict__ cm, const float* __restrict__ bias_r,
    const float* __restrict__ w_out, const float* __restrict__ b_out,
    float* __restrict__ out) {
  __shared__ i32x4 hAv[4 * 64];               // 4 KB: h as i8 A-frags [kc][lane][16B]
  __shared__ int mhs[RR * N3];                // 24 KB: i32 mh exchange

  int g = blockIdx.x;                          // row group 0..15
  int tid = threadIdx.x;
  int lane = tid & 63;
  int wv = tid >> 6;                           // wave 0..7 == gate row 0..7

  // persistent weight fragments: wave wv owns ntiles [wv*6, wv*6+6) -> 96 VGPRs
  i32x4 bq[QW][4];
  {
    const i32x4* wsrc = (const i32x4*)w8 + lane;
#pragma unroll
    for (int q = 0; q < QW; ++q)
#pragma unroll
      for (int kc = 0; kc < 4; ++kc)
        bq[q][kc] = wsrc[(size_t)((wv * QW + q) * 4 + kc) * 64];
  }
  if (tid < 256) { i32x4 z = {0, 0, 0, 0}; hAv[tid] = z; }

  int grow = g * RR + wv;                      // global batch row (gate side)

  float hreg[4];
#pragma unroll
  for (int j = 0; j < 4; ++j) hreg[j] = 0.0f;

  // gate loop-invariants: units u = lane + 64j
  float brc[4], gz[4], gr[4], gc[4];
#pragma unroll
  for (int j = 0; j < 4; ++j) {
    int u = lane + 64 * j;
    brc[j] = bias_r[2 * UNITS + u];
    float inv = 1.0f / (127.0f * 127.0f);
    gz[j] = cm[u] * inv;
    gr[j] = cm[u + UNITS] * inv;
    gc[j] = cm[u + 2 * UNITS] * inv;
  }
  // hA byte-write base: unit u=lane+64j, row wv -> kc=j, dest lane la, byte e
  int la = wv + 16 * ((lane >> 2) & 3);
  int e8 = ((lane >> 4) & 3) * 4 + (lane & 3);
  signed char* hAb = (signed char*)hAv + la * 16 + e8;

  int r0 = (lane >> 4) * 4;                    // D-frag row base
  int colb = wv * (QW * 16) + (lane & 15);     // D-frag col base
  const unsigned short* mxr = MX + (size_t)grow * N3 + lane;

  __syncthreads();

  for (int t = 0; t < T_STEPS; ++t) {
    // prefetch mx for this step (consumed after barrier -> hidden under MFMA)
    unsigned short xzv[4], xrv[4], xcv[4];
#pragma unroll
    for (int j = 0; j < 4; ++j) {
      xzv[j] = mxr[64 * j];
      xrv[j] = mxr[64 * j + UNITS];
      xcv[j] = mxr[64 * j + 2 * UNITS];
    }
    mxr += (size_t)BATCH * N3;

    // A-fragments of h (i8, M=16 rows 8..15 zero)
    i32x4 af[4];
#pragma unroll
    for (int kc = 0; kc < 4; ++kc) af[kc] = hAv[kc * 64 + lane];

    // GEMV: 6 ntiles x 4 K-chunks of 64
    i32x4 acc[QW];
#pragma unroll
    for (int q = 0; q < QW; ++q) { i32x4 z = {0, 0, 0, 0}; acc[q] = z; }
#pragma unroll
    for (int kc = 0; kc < 4; ++kc)
#pragma unroll
      for (int q = 0; q < QW; ++q)
        acc[q] = __builtin_amdgcn_mfma_i32_16x16x64_i8(af[kc], bq[q][kc], acc[q], 0, 0, 0);

    if (r0 < RR) {                             // D rows 0..7 valid (lanes 0..31)
#pragma unroll
      for (int q = 0; q < QW; ++q)
#pragma unroll
        for (int j = 0; j < 4; ++j)
          mhs[(r0 + j) * N3 + colb + q * 16] = acc[q][j];
    }

    __syncthreads();   // mh visible; all a-frag reads done

    // gate phase: wave wv handles row wv, lane handles units lane+64j (stride-1 reads)
    const int* mhr = mhs + wv * N3 + lane;
#pragma unroll
    for (int j = 0; j < 4; ++j) {
      float mz = (float)mhr[64 * j] * gz[j];
      float mr = (float)mhr[64 * j + UNITS] * gr[j];
      float mc = (float)mhr[64 * j + 2 * UNITS] * gc[j];
      float xz = bf2f(xzv[j]);
      float xr = bf2f(xrv[j]);
      float xc = bf2f(xcv[j]);
      float z = sigmoidf_(xz + mz);            // bias_i + bias_r(z) folded into MX
      float r = sigmoidf_(xr + mr);            // bias_i + bias_r(r) folded into MX
      float cand = tanhf_(xc + r * (mc + brc[j]));  // bias_r(c) inside r*(...)
      hreg[j] = z * hreg[j] + (1.0f - z) * cand;
      int h8 = (int)rintf(hreg[j] * 127.0f);
      hAb[j * 1024] = (signed char)h8;         // kc=j plane
    }
    __syncthreads();
  }

  // output: logits = h @ w_out + b_out -> sigmoid
  {
    float p = 0.0f;
#pragma unroll
    for (int j = 0; j < 4; ++j) p += hreg[j] * w_out[lane + 64 * j];
    p += __shfl_down(p, 32, 64);
    p += __shfl_down(p, 16, 64);
    p += __shfl_down(p, 8, 64);
    p += __shfl_down(p, 4, 64);
    p += __shfl_down(p, 2, 64);
    p += __shfl_down(p, 1, 64);
    if (lane == 0) out[grow] = sigmoidf_(p + b_out[0]);
  }
}

extern "C" void kernel_launch(void* const* d_in, const int* in_sizes, int n_in,
                              void* d_out, int out_size, void* d_ws, size_t ws_size,
                              hipStream_t stream) {
  const int*   inputs = (const int*)d_in[0];
  const float* emb    = (const float*)d_in[1];
  const float* kern   = (const float*)d_in[2];
  const float* rkern  = (const float*)d_in[3];
  const float* bias_i = (const float*)d_in[4];
  const float* bias_r = (const float*)d_in[5];
  const float* w_out  = (const float*)d_in[6];
  const float* b_out  = (const float*)d_in[7];
  float* out = (float*)d_out;

  char* ws = (char*)d_ws;
  size_t off = 0;
  unsigned short* MX  = (unsigned short*)(ws + off); off += (size_t)T_STEPS * BATCH * N3 * 2; // 39.3 MB
  signed char*    w8  = (signed char*)(ws + off);    off += (size_t)W8_BYTES;                 // 192 KB
  unsigned short* wfx = (unsigned short*)(ws + off); off += (size_t)WFX_ELEMS * 2;            // 192 KB
  float* cm   = (float*)(ws + off); off += (size_t)N3 * 4;
  float* bsum = (float*)(ws + off); off += (size_t)N3 * 4;
  if (off > ws_size) return;  // insufficient scratch -> visible failure, no corruption

  scale_kernel<<<dim3(3), dim3(256), 0, stream>>>(rkern, cm);
  int prep_total = W8_BYTES + WFX_ELEMS + N3;
  prep_kernel<<<dim3((prep_total + 255) / 256), dim3(256), 0, stream>>>(
      kern, rkern, bias_i, bias_r, cm, w8, wfx, bsum);
  mx_kernel<<<dim3(1600), dim3(256), 0, stream>>>(inputs, emb, wfx, bsum, MX);
  gru_kernel<<<dim3(NG), dim3(512), 0, stream>>>(MX, w8, cm, bias_r, w_out, b_out, out);
}

// Round 5
// 321.790 us; speedup vs baseline: 5.0501x; 1.2534x over previous
//
#include <hip/hip_runtime.h>
#include <stdint.h>

typedef __attribute__((ext_vector_type(8))) short short8;
typedef __attribute__((ext_vector_type(4))) float f32x4;
typedef __attribute__((ext_vector_type(4))) int   i32x4;
typedef __attribute__((ext_vector_type(4))) unsigned int u32x4;
typedef __attribute__((ext_vector_type(2))) unsigned int u32x2;

#define T_STEPS 200
#define BATCH   128
#define UNITS   256
#define N3      768
#define EMB_D   100

#define NG 8        // row groups (blocks in gru kernel)
#define RR 16       // batch rows per group (fills M=16 exactly)
#define GWAVES 16   // waves per gru block

#define W8_BYTES  (48 * 4 * 64 * 16)         // 196608 == 256*768 i8 frags
#define WFX_ELEMS (48 * 4 * 64 * 8)          // 98304  == 128*768 bf16 (K padded 100->128)
#define MX2_SLICE (16 * 64 * 12)             // ushorts per (t,g) slice == 16x768

__device__ __forceinline__ unsigned short f2bf(float f) {
  unsigned int u = __float_as_uint(f);
  u = (u + 0x7fffu + ((u >> 16) & 1u)) >> 16;   // RNE
  return (unsigned short)u;
}
__device__ __forceinline__ float sigmoidf_(float x) {
  return __builtin_amdgcn_rcpf(1.0f + __expf(-x));
}
__device__ __forceinline__ float tanhf_(float x) {
  return 1.0f - 2.0f * __builtin_amdgcn_rcpf(1.0f + __expf(2.0f * x));
}

// ---------------- kernel 0a: per-column absmax of rkernel -> cm[768] ----------------
__global__ void scale_kernel(const float* __restrict__ rkern, float* __restrict__ cm) {
  int n = blockIdx.x * 256 + threadIdx.x;
  if (n >= N3) return;
  float m = 0.0f;
  for (int k = 0; k < UNITS; ++k) m = fmaxf(m, fabsf(rkern[k * N3 + n]));
  cm[n] = (m > 0.0f) ? m : 1.0f;
}

// ---------------- kernel 0b: quantize rkernel->i8 frags, kernel->bf16 frags, bsum ---
__global__ void prep_kernel(const float* __restrict__ kern,
                            const float* __restrict__ rkern,
                            const float* __restrict__ bias_i,
                            const float* __restrict__ bias_r,
                            const float* __restrict__ cm,
                            signed char* __restrict__ w8,
                            unsigned short* __restrict__ wfx,
                            float* __restrict__ bsum) {
  int i = blockIdx.x * 256 + threadIdx.x;
  if (i < W8_BYTES) {
    // byte i = ((ntg*4 + kc)*64 + l)*16 + e  ->  rkernel[k][n] / cm[n] * 127
    int e = i & 15, l = (i >> 4) & 63, kc = (i >> 10) & 3, ntg = i >> 12;
    int r = (e & 3) + ((l >> 4) & 3) * 4 + ((e >> 2) & 3) * 16;  // k within 64-chunk
    int k = kc * 64 + r;
    int n = ntg * 16 + (l & 15);
    float v = rintf(rkern[k * N3 + n] * 127.0f / cm[n]);
    v = fminf(127.0f, fmaxf(-127.0f, v));
    w8[i] = (signed char)(int)v;
  } else if (i < W8_BYTES + WFX_ELEMS) {
    int j = i - W8_BYTES;
    int e = j & 7, l = (j >> 3) & 63, ks = (j >> 9) & 3, nt = j >> 11;
    int k = ks * 32 + (e >> 2) * 16 + ((l >> 4) & 3) * 4 + (e & 3);
    int n = nt * 16 + (l & 15);
    wfx[j] = (k < EMB_D) ? f2bf(kern[k * N3 + n]) : (unsigned short)0;
  } else if (i < W8_BYTES + WFX_ELEMS + N3) {
    int c = i - (W8_BYTES + WFX_ELEMS);
    bsum[c] = bias_i[c] + ((c < 2 * UNITS) ? bias_r[c] : 0.0f);
  }
}

// -------- kernel 1: MX2 = gru-lane-ordered bf16 (emb[inputs] @ kernel + bsum) --------
// MX2 layout: [(t*8+g)][wv 0..15][lane 0..63][12]: per lane 12 ushorts =
// [z j=0..3][r j=0..3][c j=0..3] for (row=(lane>>4)*4+j, u=wv*16+(lane&15)).
__global__ __launch_bounds__(256) void mx_kernel(
    const int* __restrict__ inputs, const float* __restrict__ emb,
    const unsigned short* __restrict__ wfx, const float* __restrict__ bsum,
    unsigned short* __restrict__ MX2) {
  __shared__ unsigned short Af[4 * 64 * 8];   // 4 KB A-fragments (16 rows x K128)
  __shared__ unsigned short stg[MX2_SLICE];   // 24 KB scatter staging
  int tile = blockIdx.x;                      // tile == t*8 + g  (1600 tiles)
  int tid = threadIdx.x;
  int lane = tid & 63;
  int wv = tid >> 6;
  {
    short8 z = {0, 0, 0, 0, 0, 0, 0, 0};
    ((short8*)Af)[tid] = z;
  }
  __syncthreads();
  for (int e = tid; e < 16 * EMB_D; e += 256) {
    int r = e / EMB_D;
    int c = e - r * EMB_D;
    int m = tile * 16 + r;                    // m = t*128 + b
    int ti = m >> 7, b = m & 127;
    int word = inputs[b * T_STEPS + ti];
    float v = emb[word * EMB_D + c];
    int idx = ((c >> 5) * 64 + (r + 16 * ((c >> 2) & 3))) * 8 + ((c >> 4) & 1) * 4 + (c & 3);
    Af[idx] = f2bf(v);
  }
  __syncthreads();
  short8 a0 = ((short8*)Af)[0 * 64 + lane];
  short8 a1 = ((short8*)Af)[1 * 64 + lane];
  short8 a2 = ((short8*)Af)[2 * 64 + lane];
  short8 a3 = ((short8*)Af)[3 * 64 + lane];
  int laneg_base = (lane >> 4) * 16;          // ((row>>2)<<4), row = (lane>>4)*4 + j
  for (int q = 0; q < 12; ++q) {
    int nt = wv * 12 + q;
    f32x4 acc = {0.f, 0.f, 0.f, 0.f};
    const short8* bp = (const short8*)(wfx) + (nt * 4) * 64 + lane;
    acc = __builtin_amdgcn_mfma_f32_16x16x32_bf16(a0, bp[0],   acc, 0, 0, 0);
    acc = __builtin_amdgcn_mfma_f32_16x16x32_bf16(a1, bp[64],  acc, 0, 0, 0);
    acc = __builtin_amdgcn_mfma_f32_16x16x32_bf16(a2, bp[128], acc, 0, 0, 0);
    acc = __builtin_amdgcn_mfma_f32_16x16x32_bf16(a3, bp[192], acc, 0, 0, 0);
    int col = nt * 16 + (lane & 15);
    float bs = bsum[col];
    int gate = col >> 8, u = col & 255;
    int laneg = laneg_base | (u & 15);
    int base = ((u >> 4) * 64 + laneg) * 12 + gate * 4;
#pragma unroll
    for (int j = 0; j < 4; ++j) stg[base + j] = f2bf(acc[j] + bs);
  }
  __syncthreads();
  const u32x4* s = (const u32x4*)stg;
  u32x4* d = (u32x4*)(MX2 + (size_t)tile * MX2_SLICE);
  for (int i = tid; i < MX2_SLICE / 8; i += 256) d[i] = s[i];
}

// -------- kernel 2: block-local GRU, i8 MFMA, gate-aligned cols, no mh exchange ------
__global__ __launch_bounds__(1024) void gru_kernel(
    const unsigned short* __restrict__ MX2, const signed char* __restrict__ w8,
    const float* __restrict__ cm, const float* __restrict__ bias_r,
    const float* __restrict__ w_out, const float* __restrict__ b_out,
    float* __restrict__ out) {
  __shared__ i32x4 hAv[2][4 * 64];            // 8 KB: double-buffered h i8 A-frags
  __shared__ float hout[RR * UNITS];          // 16 KB: final h (fp32) for output GEMV

  int g = blockIdx.x;                          // 0..7
  int tid = threadIdx.x;
  int lane = tid & 63;
  int wv = tid >> 6;                           // 0..15

  // persistent weights: wave wv owns ntile triple {wv, 16+wv, 32+wv} (z,r,c cols u..u+15)
  i32x4 bz[4], br[4], bc[4];
  {
    const i32x4* wsrc = (const i32x4*)w8 + lane;
#pragma unroll
    for (int kc = 0; kc < 4; ++kc) {
      bz[kc] = wsrc[(size_t)((wv)*4 + kc) * 64];
      br[kc] = wsrc[(size_t)((16 + wv) * 4 + kc) * 64];
      bc[kc] = wsrc[(size_t)((32 + wv) * 4 + kc) * 64];
    }
  }
  if (tid < 256) { i32x4 z = {0, 0, 0, 0}; hAv[0][tid] = z; }

  int l15 = lane & 15;
  int u = wv * 16 + l15;
  const float inv = 1.0f / (127.0f * 127.0f);
  float sz = cm[u] * inv;
  float sr = cm[u + UNITS] * inv;
  float sc = cm[u + 2 * UNITS] * inv;
  float brc = bias_r[2 * UNITS + u];
  int r0 = (lane >> 4) * 4;                    // D-frag row base == gate rows r0..r0+3

  // hA byte-write base: row r0+j, unit u -> plane kc=(wv>>2) [1024 B each],
  // lane la=16*(l15>>2)+(r0+j), byte e=(l15&3)+4*(wv&3).  Buffer stride 4096 B.
  int hwb = (wv >> 2) * 1024 + (16 * (l15 >> 2) + r0) * 16 + (l15 & 3) + 4 * (wv & 3);

  float hreg[4] = {0.0f, 0.0f, 0.0f, 0.0f};
  const unsigned short* mxp = MX2 + ((size_t)g * GWAVES + wv) * 64 * 12 + (size_t)lane * 12;
  const size_t mxstride = (size_t)NG * GWAVES * 64 * 12;

  __syncthreads();

  for (int t = 0; t < T_STEPS; ++t) {
    // prefetch this step's mx (24 B/lane), consumed after MFMAs -> latency hidden
    u32x4 v4 = *(const u32x4*)(mxp);
    u32x2 v2 = *(const u32x2*)(mxp + 8);
    mxp += mxstride;

    const i32x4* hp = &hAv[t & 1][0];
    i32x4 af0 = hp[0 * 64 + lane];
    i32x4 af1 = hp[1 * 64 + lane];
    i32x4 af2 = hp[2 * 64 + lane];
    i32x4 af3 = hp[3 * 64 + lane];

    i32x4 az = {0, 0, 0, 0}, ar = {0, 0, 0, 0}, ac = {0, 0, 0, 0};
    az = __builtin_amdgcn_mfma_i32_16x16x64_i8(af0, bz[0], az, 0, 0, 0);
    ar = __builtin_amdgcn_mfma_i32_16x16x64_i8(af0, br[0], ar, 0, 0, 0);
    ac = __builtin_amdgcn_mfma_i32_16x16x64_i8(af0, bc[0], ac, 0, 0, 0);
    az = __builtin_amdgcn_mfma_i32_16x16x64_i8(af1, bz[1], az, 0, 0, 0);
    ar = __builtin_amdgcn_mfma_i32_16x16x64_i8(af1, br[1], ar, 0, 0, 0);
    ac = __builtin_amdgcn_mfma_i32_16x16x64_i8(af1, bc[1], ac, 0, 0, 0);
    az = __builtin_amdgcn_mfma_i32_16x16x64_i8(af2, bz[2], az, 0, 0, 0);
    ar = __builtin_amdgcn_mfma_i32_16x16x64_i8(af2, br[2], ar, 0, 0, 0);
    ac = __builtin_amdgcn_mfma_i32_16x16x64_i8(af2, bc[2], ac, 0, 0, 0);
    az = __builtin_amdgcn_mfma_i32_16x16x64_i8(af3, bz[3], az, 0, 0, 0);
    ar = __builtin_amdgcn_mfma_i32_16x16x64_i8(af3, br[3], ar, 0, 0, 0);
    ac = __builtin_amdgcn_mfma_i32_16x16x64_i8(af3, bc[3], ac, 0, 0, 0);

    // unpack mx (bf16 -> f32 via shift/mask)
    float xz[4], xr[4], xc[4];
    xz[0] = __uint_as_float(v4[0] << 16); xz[1] = __uint_as_float(v4[0] & 0xffff0000u);
    xz[2] = __uint_as_float(v4[1] << 16); xz[3] = __uint_as_float(v4[1] & 0xffff0000u);
    xr[0] = __uint_as_float(v4[2] << 16); xr[1] = __uint_as_float(v4[2] & 0xffff0000u);
    xr[2] = __uint_as_float(v4[3] << 16); xr[3] = __uint_as_float(v4[3] & 0xffff0000u);
    xc[0] = __uint_as_float(v2[0] << 16); xc[1] = __uint_as_float(v2[0] & 0xffff0000u);
    xc[2] = __uint_as_float(v2[1] << 16); xc[3] = __uint_as_float(v2[1] & 0xffff0000u);

    // gate phase directly on accumulators; write h_t bytes into next buffer
    signed char* hw = (signed char*)hAv + (((t & 1) ^ 1) * 4096) + hwb;
#pragma unroll
    for (int j = 0; j < 4; ++j) {
      float zg = sigmoidf_(__fmaf_rn((float)az[j], sz, xz[j]));
      float rg = sigmoidf_(__fmaf_rn((float)ar[j], sr, xr[j]));
      float mc = __fmaf_rn((float)ac[j], sc, brc);
      float cand = tanhf_(__fmaf_rn(rg, mc, xc[j]));
      hreg[j] = cand + zg * (hreg[j] - cand);
      hw[j * 16] = (signed char)(int)rintf(hreg[j] * 127.0f);
    }
    __syncthreads();
  }

  // epilogue: logits = h @ w_out + b_out -> sigmoid
#pragma unroll
  for (int j = 0; j < 4; ++j) hout[(r0 + j) * UNITS + u] = hreg[j];
  __syncthreads();
  {
    float p = 0.0f;
#pragma unroll
    for (int k = 0; k < 4; ++k) p += hout[wv * UNITS + lane + 64 * k] * w_out[lane + 64 * k];
    p += __shfl_down(p, 32, 64);
    p += __shfl_down(p, 16, 64);
    p += __shfl_down(p, 8, 64);
    p += __shfl_down(p, 4, 64);
    p += __shfl_down(p, 2, 64);
    p += __shfl_down(p, 1, 64);
    if (lane == 0) out[g * RR + wv] = sigmoidf_(p + b_out[0]);
  }
}

extern "C" void kernel_launch(void* const* d_in, const int* in_sizes, int n_in,
                              void* d_out, int out_size, void* d_ws, size_t ws_size,
                              hipStream_t stream) {
  const int*   inputs = (const int*)d_in[0];
  const float* emb    = (const float*)d_in[1];
  const float* kern   = (const float*)d_in[2];
  const float* rkern  = (const float*)d_in[3];
  const float* bias_i = (const float*)d_in[4];
  const float* bias_r = (const float*)d_in[5];
  const float* w_out  = (const float*)d_in[6];
  const float* b_out  = (const float*)d_in[7];
  float* out = (float*)d_out;

  char* ws = (char*)d_ws;
  size_t off = 0;
  unsigned short* MX2 = (unsigned short*)(ws + off); off += (size_t)T_STEPS * 8 * MX2_SLICE * 2; // 39.3 MB
  signed char*    w8  = (signed char*)(ws + off);    off += (size_t)W8_BYTES;                    // 192 KB
  unsigned short* wfx = (unsigned short*)(ws + off); off += (size_t)WFX_ELEMS * 2;               // 192 KB
  float* cm   = (float*)(ws + off); off += (size_t)N3 * 4;
  float* bsum = (float*)(ws + off); off += (size_t)N3 * 4;
  if (off > ws_size) return;  // insufficient scratch -> visible failure, no corruption

  scale_kernel<<<dim3(3), dim3(256), 0, stream>>>(rkern, cm);
  int prep_total = W8_BYTES + WFX_ELEMS + N3;
  prep_kernel<<<dim3((prep_total + 255) / 256), dim3(256), 0, stream>>>(
      kern, rkern, bias_i, bias_r, cm, w8, wfx, bsum);
  mx_kernel<<<dim3(1600), dim3(256), 0, stream>>>(inputs, emb, wfx, bsum, MX2);
  gru_kernel<<<dim3(NG), dim3(1024), 0, stream>>>(MX2, w8, cm, bias_r, w_out, b_out, out);
}

// Round 6
// 273.733 us; speedup vs baseline: 5.9367x; 1.1756x over previous
//
#include <hip/hip_runtime.h>
#include <stdint.h>

typedef __attribute__((ext_vector_type(8))) short short8;
typedef __attribute__((ext_vector_type(4))) float f32x4;
typedef __attribute__((ext_vector_type(4))) int   i32x4;
typedef __attribute__((ext_vector_type(4))) unsigned int u32x4;
typedef __attribute__((ext_vector_type(2))) unsigned int u32x2;

#define T_STEPS 200
#define BATCH   128
#define UNITS   256
#define N3      768
#define EMB_D   100

#define NG 8        // row groups (blocks in gru kernel)
#define RR 16       // batch rows per group (fills M=16 exactly)
#define GWAVES 16   // waves per gru block

#define W8_BYTES  (48 * 4 * 64 * 16)         // 196608 == 256*768 i8 frags
#define WFX_ELEMS (48 * 4 * 64 * 8)          // 98304  == 128*768 bf16 (K padded 100->128)
#define MX2_SLICE (16 * 64 * 12)             // ushorts per (t,g) slice == 16x768

#define NLOG2E  -1.4426950408889634f         // -log2(e), folded into z/r columns
#define N2LOG2E -2.8853900817779268f         // -2*log2(e), folded into c columns

#if __has_builtin(__builtin_amdgcn_exp2f)
#define EXP2(x) __builtin_amdgcn_exp2f(x)
#else
#define EXP2(x) __expf((x) * 0.6931471805599453f)
#endif

__device__ __forceinline__ unsigned short f2bf(float f) {
  unsigned int u = __float_as_uint(f);
  u = (u + 0x7fffu + ((u >> 16) & 1u)) >> 16;   // RNE
  return (unsigned short)u;
}
__device__ __forceinline__ float sigmoidf_(float x) {
  return __builtin_amdgcn_rcpf(1.0f + __expf(-x));
}

// ---------------- kernel 0a: per-column absmax of rkernel -> cm[768] ----------------
// 24 blocks x 256: block owns 32 cols; thread (t&31)=col, (t>>5)=k-slice of 32.
__global__ void scale_kernel(const float* __restrict__ rkern, float* __restrict__ cm) {
  __shared__ float red[256];
  int t = threadIdx.x;
  int n = blockIdx.x * 32 + (t & 31);
  int k0 = (t >> 5) * 32;
  float m = 0.0f;
#pragma unroll 8
  for (int k = k0; k < k0 + 32; ++k) m = fmaxf(m, fabsf(rkern[k * N3 + n]));
  red[t] = m;
  __syncthreads();
  if (t < 32) {
    float mm = red[t];
#pragma unroll
    for (int s = 1; s < 8; ++s) mm = fmaxf(mm, red[t + 32 * s]);
    cm[blockIdx.x * 32 + t] = (mm > 0.0f) ? mm : 1.0f;
  }
}

// ------- kernel 0b: quantize rkernel->i8 frags; kernel->bf16 frags (log2e-folded) ----
__global__ void prep_kernel(const float* __restrict__ kern,
                            const float* __restrict__ rkern,
                            const float* __restrict__ bias_i,
                            const float* __restrict__ bias_r,
                            const float* __restrict__ cm,
                            signed char* __restrict__ w8,
                            unsigned short* __restrict__ wfx,
                            float* __restrict__ bsum) {
  int i = blockIdx.x * 256 + threadIdx.x;
  if (i < W8_BYTES) {
    // byte i = ((ntg*4 + kc)*64 + l)*16 + e  ->  rkernel[k][n] / cm[n] * 127
    int e = i & 15, l = (i >> 4) & 63, kc = (i >> 10) & 3, ntg = i >> 12;
    int r = (e & 3) + ((l >> 4) & 3) * 4 + ((e >> 2) & 3) * 16;  // k within 64-chunk
    int k = kc * 64 + r;
    int n = ntg * 16 + (l & 15);
    float v = rintf(rkern[k * N3 + n] * 127.0f / cm[n]);
    v = fminf(127.0f, fmaxf(-127.0f, v));
    w8[i] = (signed char)(int)v;
  } else if (i < W8_BYTES + WFX_ELEMS) {
    int j = i - W8_BYTES;
    int e = j & 7, l = (j >> 3) & 63, ks = (j >> 9) & 3, nt = j >> 11;
    int k = ks * 32 + (e >> 2) * 16 + ((l >> 4) & 3) * 4 + (e & 3);
    int n = nt * 16 + (l & 15);
    float gf = (n < 2 * UNITS) ? NLOG2E : N2LOG2E;   // fold exp2 scale into columns
    wfx[j] = (k < EMB_D) ? f2bf(kern[k * N3 + n] * gf) : (unsigned short)0;
  } else if (i < W8_BYTES + WFX_ELEMS + N3) {
    int c = i - (W8_BYTES + WFX_ELEMS);
    float gf = (c < 2 * UNITS) ? NLOG2E : N2LOG2E;
    bsum[c] = (bias_i[c] + ((c < 2 * UNITS) ? bias_r[c] : 0.0f)) * gf;
  }
}

// -------- kernel 1: MX2 = gru-lane-ordered bf16 (emb[inputs] @ kernel' + bsum') ------
// MX2 layout: [(t*8+g)][wv 0..15][lane 0..63][12]: per lane 12 ushorts =
// [z j=0..3][r j=0..3][c j=0..3] for (row=(lane>>4)*4+j, u=wv*16+(lane&15)).
// Values carry the -log2e / -2log2e fold (done in wfx/bsum).
__global__ __launch_bounds__(256) void mx_kernel(
    const int* __restrict__ inputs, const float* __restrict__ emb,
    const unsigned short* __restrict__ wfx, const float* __restrict__ bsum,
    unsigned short* __restrict__ MX2) {
  __shared__ unsigned short Af[4 * 64 * 8];   // 4 KB A-fragments (16 rows x K128)
  __shared__ unsigned short stg[MX2_SLICE];   // 24 KB scatter staging
  int tile = blockIdx.x;                      // tile == t*8 + g  (1600 tiles)
  int tid = threadIdx.x;
  int lane = tid & 63;
  int wv = tid >> 6;
  {
    short8 z = {0, 0, 0, 0, 0, 0, 0, 0};
    ((short8*)Af)[tid] = z;
  }
  __syncthreads();
  for (int e = tid; e < 16 * EMB_D; e += 256) {
    int r = e / EMB_D;
    int c = e - r * EMB_D;
    int m = tile * 16 + r;                    // m = t*128 + b
    int ti = m >> 7, b = m & 127;
    int word = inputs[b * T_STEPS + ti];
    float v = emb[word * EMB_D + c];
    int idx = ((c >> 5) * 64 + (r + 16 * ((c >> 2) & 3))) * 8 + ((c >> 4) & 1) * 4 + (c & 3);
    Af[idx] = f2bf(v);
  }
  __syncthreads();
  short8 a0 = ((short8*)Af)[0 * 64 + lane];
  short8 a1 = ((short8*)Af)[1 * 64 + lane];
  short8 a2 = ((short8*)Af)[2 * 64 + lane];
  short8 a3 = ((short8*)Af)[3 * 64 + lane];
  int laneg_base = (lane >> 4) * 16;          // ((row>>2)<<4), row = (lane>>4)*4 + j
  for (int q = 0; q < 12; ++q) {
    int nt = wv * 12 + q;
    f32x4 acc = {0.f, 0.f, 0.f, 0.f};
    const short8* bp = (const short8*)(wfx) + (nt * 4) * 64 + lane;
    acc = __builtin_amdgcn_mfma_f32_16x16x32_bf16(a0, bp[0],   acc, 0, 0, 0);
    acc = __builtin_amdgcn_mfma_f32_16x16x32_bf16(a1, bp[64],  acc, 0, 0, 0);
    acc = __builtin_amdgcn_mfma_f32_16x16x32_bf16(a2, bp[128], acc, 0, 0, 0);
    acc = __builtin_amdgcn_mfma_f32_16x16x32_bf16(a3, bp[192], acc, 0, 0, 0);
    int col = nt * 16 + (lane & 15);
    float bs = bsum[col];
    int gate = col >> 8, u = col & 255;
    int laneg = laneg_base | (u & 15);
    int base = ((u >> 4) * 64 + laneg) * 12 + gate * 4;
#pragma unroll
    for (int j = 0; j < 4; ++j) stg[base + j] = f2bf(acc[j] + bs);
  }
  __syncthreads();
  const u32x4* s = (const u32x4*)stg;
  u32x4* d = (u32x4*)(MX2 + (size_t)tile * MX2_SLICE);
  for (int i = tid; i < MX2_SLICE / 8; i += 256) d[i] = s[i];
}

// -------- kernel 2: block-local GRU, i8 MFMA, staged MFMA/VALU interleave ------------
__global__ __launch_bounds__(1024) void gru_kernel(
    const unsigned short* __restrict__ MX2, const signed char* __restrict__ w8,
    const float* __restrict__ cm, const float* __restrict__ bias_r,
    const float* __restrict__ w_out, const float* __restrict__ b_out,
    float* __restrict__ out) {
  __shared__ i32x4 hAv[2][4 * 64];            // 8 KB: double-buffered h i8 A-frags
  __shared__ float hout[RR * UNITS];          // 16 KB: final h (fp32) for output GEMV

  int g = blockIdx.x;                          // 0..7
  int tid = threadIdx.x;
  int lane = tid & 63;
  int wv = tid >> 6;                           // 0..15

  // persistent weights: wave wv owns ntile triple {wv, 16+wv, 32+wv} (z,r,c cols u..u+15)
  i32x4 bz[4], br[4], bc[4];
  {
    const i32x4* wsrc = (const i32x4*)w8 + lane;
#pragma unroll
    for (int kc = 0; kc < 4; ++kc) {
      bz[kc] = wsrc[(size_t)((wv)*4 + kc) * 64];
      br[kc] = wsrc[(size_t)((16 + wv) * 4 + kc) * 64];
      bc[kc] = wsrc[(size_t)((32 + wv) * 4 + kc) * 64];
    }
  }
  if (tid < 256) { i32x4 z = {0, 0, 0, 0}; hAv[0][tid] = z; }

  int l15 = lane & 15;
  int u = wv * 16 + l15;
  const float inv = 1.0f / (127.0f * 127.0f);
  float szp = cm[u] * inv * NLOG2E;            // -log2e * scale_z
  float srp = cm[u + UNITS] * inv * NLOG2E;    // -log2e * scale_r
  float scp = cm[u + 2 * UNITS] * inv * N2LOG2E;  // -2log2e * scale_c
  float brcp = bias_r[2 * UNITS + u] * N2LOG2E;   // -2log2e * bias_r(c)
  int r0 = (lane >> 4) * 4;                    // D-frag row base == gate rows r0..r0+3

  // hA byte-write base: row r0+j, unit u -> plane kc=(wv>>2) [1024 B each],
  // lane la=16*(l15>>2)+(r0+j), byte e=(l15&3)+4*(wv&3).  Buffer stride 4096 B.
  int hwb = (wv >> 2) * 1024 + (16 * (l15 >> 2) + r0) * 16 + (l15 & 3) + 4 * (wv & 3);

  float hreg[4] = {0.0f, 0.0f, 0.0f, 0.0f};
  const unsigned short* mxp = MX2 + ((size_t)g * GWAVES + wv) * 64 * 12 + (size_t)lane * 12;
  const size_t mxstride = (size_t)NG * GWAVES * 64 * 12;
  const float MAGIC = 12582912.0f;             // 2^23 + 2^22: fma(h,127,MAGIC) -> low byte

  __syncthreads();

  for (int t = 0; t < T_STEPS; ++t) {
    // prefetch this step's mx (24 B/lane, pre-scaled), consumed in gate stages
    u32x4 v4 = *(const u32x4*)(mxp);
    u32x2 v2 = *(const u32x2*)(mxp + 8);
    mxp += mxstride;

    const i32x4* hp = &hAv[t & 1][0];
    i32x4 af0 = hp[0 * 64 + lane];
    i32x4 af1 = hp[1 * 64 + lane];
    i32x4 af2 = hp[2 * 64 + lane];
    i32x4 af3 = hp[3 * 64 + lane];

    // ---- z chain ----
    i32x4 az = {0, 0, 0, 0};
    az = __builtin_amdgcn_mfma_i32_16x16x64_i8(af0, bz[0], az, 0, 0, 0);
    az = __builtin_amdgcn_mfma_i32_16x16x64_i8(af1, bz[1], az, 0, 0, 0);
    az = __builtin_amdgcn_mfma_i32_16x16x64_i8(af2, bz[2], az, 0, 0, 0);
    az = __builtin_amdgcn_mfma_i32_16x16x64_i8(af3, bz[3], az, 0, 0, 0);
    // ---- z stage (overlaps r/c chains below) ----
    float tz[4];
    {
      float xz0 = __uint_as_float(v4[0] << 16), xz1 = __uint_as_float(v4[0] & 0xffff0000u);
      float xz2 = __uint_as_float(v4[1] << 16), xz3 = __uint_as_float(v4[1] & 0xffff0000u);
      tz[0] = 1.0f + EXP2(fminf(__fmaf_rn((float)az[0], szp, xz0), 30.0f));
      tz[1] = 1.0f + EXP2(fminf(__fmaf_rn((float)az[1], szp, xz1), 30.0f));
      tz[2] = 1.0f + EXP2(fminf(__fmaf_rn((float)az[2], szp, xz2), 30.0f));
      tz[3] = 1.0f + EXP2(fminf(__fmaf_rn((float)az[3], szp, xz3), 30.0f));
    }
    // ---- r chain ----
    i32x4 ar = {0, 0, 0, 0};
    ar = __builtin_amdgcn_mfma_i32_16x16x64_i8(af0, br[0], ar, 0, 0, 0);
    ar = __builtin_amdgcn_mfma_i32_16x16x64_i8(af1, br[1], ar, 0, 0, 0);
    ar = __builtin_amdgcn_mfma_i32_16x16x64_i8(af2, br[2], ar, 0, 0, 0);
    ar = __builtin_amdgcn_mfma_i32_16x16x64_i8(af3, br[3], ar, 0, 0, 0);
    // ---- r stage: shared rcp with z ----
    float zg[4], rg[4];
    {
      float xr0 = __uint_as_float(v4[2] << 16), xr1 = __uint_as_float(v4[2] & 0xffff0000u);
      float xr2 = __uint_as_float(v4[3] << 16), xr3 = __uint_as_float(v4[3] & 0xffff0000u);
      float tr0 = 1.0f + EXP2(fminf(__fmaf_rn((float)ar[0], srp, xr0), 30.0f));
      float tr1 = 1.0f + EXP2(fminf(__fmaf_rn((float)ar[1], srp, xr1), 30.0f));
      float tr2 = 1.0f + EXP2(fminf(__fmaf_rn((float)ar[2], srp, xr2), 30.0f));
      float tr3 = 1.0f + EXP2(fminf(__fmaf_rn((float)ar[3], srp, xr3), 30.0f));
      float R0 = __builtin_amdgcn_rcpf(tz[0] * tr0);
      float R1 = __builtin_amdgcn_rcpf(tz[1] * tr1);
      float R2 = __builtin_amdgcn_rcpf(tz[2] * tr2);
      float R3 = __builtin_amdgcn_rcpf(tz[3] * tr3);
      zg[0] = tr0 * R0; rg[0] = tz[0] * R0;
      zg[1] = tr1 * R1; rg[1] = tz[1] * R1;
      zg[2] = tr2 * R2; rg[2] = tz[2] * R2;
      zg[3] = tr3 * R3; rg[3] = tz[3] * R3;
    }
    // ---- c chain ----
    i32x4 ac = {0, 0, 0, 0};
    ac = __builtin_amdgcn_mfma_i32_16x16x64_i8(af0, bc[0], ac, 0, 0, 0);
    ac = __builtin_amdgcn_mfma_i32_16x16x64_i8(af1, bc[1], ac, 0, 0, 0);
    ac = __builtin_amdgcn_mfma_i32_16x16x64_i8(af2, bc[2], ac, 0, 0, 0);
    ac = __builtin_amdgcn_mfma_i32_16x16x64_i8(af3, bc[3], ac, 0, 0, 0);
    // ---- c stage + h update + quantized writeback ----
    signed char* hw = (signed char*)hAv + (((t & 1) ^ 1) * 4096) + hwb;
    {
      float xc[4];
      xc[0] = __uint_as_float(v2[0] << 16); xc[1] = __uint_as_float(v2[0] & 0xffff0000u);
      xc[2] = __uint_as_float(v2[1] << 16); xc[3] = __uint_as_float(v2[1] & 0xffff0000u);
#pragma unroll
      for (int j = 0; j < 4; ++j) {
        float mc = __fmaf_rn((float)ac[j], scp, brcp);      // -2log2e*(mh_c + b_c)
        float Rc = __builtin_amdgcn_rcpf(1.0f + EXP2(__fmaf_rn(rg[j], mc, xc[j])));
        float cand = __fmaf_rn(2.0f, Rc, -1.0f);            // tanh
        hreg[j] = __fmaf_rn(zg[j], hreg[j] - cand, cand);
        float q = __fmaf_rn(hreg[j], 127.0f, MAGIC);        // RNE int in low mantissa
        hw[j * 16] = (signed char)(__float_as_uint(q) & 0xFF);
      }
    }
    __syncthreads();
  }

  // epilogue: logits = h @ w_out + b_out -> sigmoid
#pragma unroll
  for (int j = 0; j < 4; ++j) hout[(r0 + j) * UNITS + u] = hreg[j];
  __syncthreads();
  {
    float p = 0.0f;
#pragma unroll
    for (int k = 0; k < 4; ++k) p += hout[wv * UNITS + lane + 64 * k] * w_out[lane + 64 * k];
    p += __shfl_down(p, 32, 64);
    p += __shfl_down(p, 16, 64);
    p += __shfl_down(p, 8, 64);
    p += __shfl_down(p, 4, 64);
    p += __shfl_down(p, 2, 64);
    p += __shfl_down(p, 1, 64);
    if (lane == 0) out[g * RR + wv] = sigmoidf_(p + b_out[0]);
  }
}

extern "C" void kernel_launch(void* const* d_in, const int* in_sizes, int n_in,
                              void* d_out, int out_size, void* d_ws, size_t ws_size,
                              hipStream_t stream) {
  const int*   inputs = (const int*)d_in[0];
  const float* emb    = (const float*)d_in[1];
  const float* kern   = (const float*)d_in[2];
  const float* rkern  = (const float*)d_in[3];
  const float* bias_i = (const float*)d_in[4];
  const float* bias_r = (const float*)d_in[5];
  const float* w_out  = (const float*)d_in[6];
  const float* b_out  = (const float*)d_in[7];
  float* out = (float*)d_out;

  char* ws = (char*)d_ws;
  size_t off = 0;
  unsigned short* MX2 = (unsigned short*)(ws + off); off += (size_t)T_STEPS * 8 * MX2_SLICE * 2; // 39.3 MB
  signed char*    w8  = (signed char*)(ws + off);    off += (size_t)W8_BYTES;                    // 192 KB
  unsigned short* wfx = (unsigned short*)(ws + off); off += (size_t)WFX_ELEMS * 2;               // 192 KB
  float* cm   = (float*)(ws + off); off += (size_t)N3 * 4;
  float* bsum = (float*)(ws + off); off += (size_t)N3 * 4;
  if (off > ws_size) return;  // insufficient scratch -> visible failure, no corruption

  scale_kernel<<<dim3(24), dim3(256), 0, stream>>>(rkern, cm);
  int prep_total = W8_BYTES + WFX_ELEMS + N3;
  prep_kernel<<<dim3((prep_total + 255) / 256), dim3(256), 0, stream>>>(
      kern, rkern, bias_i, bias_r, cm, w8, wfx, bsum);
  mx_kernel<<<dim3(1600), dim3(256), 0, stream>>>(inputs, emb, wfx, bsum, MX2);
  gru_kernel<<<dim3(NG), dim3(1024), 0, stream>>>(MX2, w8, cm, bias_r, w_out, b_out, out);
}